// Round 1
// 361.725 us; speedup vs baseline: 1.0541x; 1.0541x over previous
//
#include <hip/hip_runtime.h>
#include <stdint.h>

#define BB 8
#define SS 2048
#define DD 1024
#define KREAL 204

typedef __attribute__((ext_vector_type(8))) short short8;
typedef __attribute__((ext_vector_type(4))) float floatx4;
typedef uint16_t u16;
typedef uint32_t u32;

__device__ __forceinline__ float bf2f(u16 u) {
    union { float f; u32 i; } c; c.i = ((u32)u) << 16; return c.f;
}
__device__ __forceinline__ u16 f2bf(float f) {
    union { float f; u32 i; } c; c.f = f;
    u32 i = c.i;
    u32 r = (i + 0x7FFFu + ((i >> 16) & 1u)) >> 16;
    return (u16)r;
}

#if defined(__has_builtin)
#if __has_builtin(__builtin_amdgcn_global_load_lds)
#define HAVE_GLL 1
#endif
#endif

__device__ __forceinline__ void gload16(const u16* g, u16* l) {
#ifdef HAVE_GLL
    __builtin_amdgcn_global_load_lds(
        (const __attribute__((address_space(1))) void*)(uintptr_t)g,
        (__attribute__((address_space(3))) void*)(u32)(uintptr_t)(void*)l,
        16, 0, 0);
#else
    *(uint4*)l = *(const uint4*)g;
#endif
}

#define VM_WAIT(N) asm volatile("s_waitcnt vmcnt(" #N ")" ::: "memory")
#define S_BAR()    asm volatile("s_barrier" ::: "memory")

// ===========================================================================
// Legacy 64-wide-row swizzled staging (kept for k_gemm64 only).
// ===========================================================================
__device__ __forceinline__ void stage64(const u16* __restrict__ src, size_t ld,
                                        u16* lds, int tid) {
#pragma unroll
    for (int j = 0; j < 2; j++) {
        int flat = j * 256 + tid;
        int row = flat >> 3, slot = flat & 7;
        int kg = slot ^ (row & 7);
        gload16(src + (size_t)row * ld + kg * 8, lds + flat * 8);
    }
}
__device__ __forceinline__ short8 frag(const u16* lds, int row, int kslot) {
    return *(const short8*)&lds[(row << 6) + (((kslot ^ (row & 7)) & 7) << 3)];
}

// ===========================================================================
// 256x256 8-phase GEMM core (8 waves, BK=64 split into two K-half planes of
// 32). LDS = 128 KiB: A planes [parity][kh] 256x32 @ (p*2+kh)*8192, B same
// at +32768. Staging is global_load_lds with pre-swizzled SOURCE
// (kg = slot ^ ((row>>1)&3)); frag reads apply the matching XOR -> max
// 2-way bank aliasing (free). Counted-vmcnt protocol (never 0 in main loop):
//   tile t: VM(8);BAR; issue(t+1,A,k1); P1[ldA mt0-3 + ldB, 16 MFMA];
//           issue(t+1,B,k1); P2[ldA mt4-7, 16 MFMA];
//           VM(8);BAR; issue(t+2,A,k0); P3; issue(t+2,B,k0); P4;
// Slot-reuse safety: every issue lands after the barrier that follows the
// last reader of the previous occupant (verified per-slot). Tail peeled
// with VM(4)/VM(0).
// ===========================================================================
__device__ __forceinline__ short8 frag32(const u16* plane, int row, int ks) {
    return *(const short8*)&plane[(row << 5) + (((ks ^ ((row >> 1) & 3)) & 3) << 3)];
}

__device__ __forceinline__ void stage_half(const u16* s0, const u16* s1,
                                           u16* dp, int tid) {
    gload16(s0, dp + tid * 8);
    gload16(s1, dp + 4096 + tid * 8);
}

template <int MT, bool LOADB>
__device__ __forceinline__ void phase16(const u16* Apl, const u16* Bpl,
                                        int arow, int brow, int ln, int quad,
                                        short8 (&bv)[4], floatx4 (&acc)[8][4]) {
    short8 af[4];
#pragma unroll
    for (int i = 0; i < 4; i++) af[i] = frag32(Apl, arow + (MT + i) * 16 + ln, quad);
    if (LOADB) {
#pragma unroll
        for (int nt = 0; nt < 4; nt++) bv[nt] = frag32(Bpl, brow + nt * 16 + ln, quad);
    }
    __builtin_amdgcn_s_setprio(1);
#pragma unroll
    for (int i = 0; i < 4; i++)
#pragma unroll
        for (int nt = 0; nt < 4; nt++)
            acc[MT + i][nt] = __builtin_amdgcn_mfma_f32_16x16x32_bf16(
                af[i], bv[nt], acc[MT + i][nt], 0, 0, 0);
    __builtin_amdgcn_s_setprio(0);
}

template <int NT>
__device__ __forceinline__ void gemm_core256(
    const u16* __restrict__ Ag, size_t lda,
    const u16* __restrict__ Bg, size_t ldb,
    u16* lds, int tid, floatx4 (&acc)[8][4]) {
    const int lane = tid & 63, w = tid >> 6;
    const int arow = (w >> 2) * 128, brow = (w & 3) * 64;
    const int ln = lane & 15, quad = lane >> 4;
    const int srow = tid >> 2;
    const int kgp = (tid & 3) ^ ((srow >> 1) & 3);
    const u16* A0 = Ag + (size_t)srow * lda + kgp * 8;
    const u16* A1 = Ag + (size_t)(srow + 128) * lda + kgp * 8;
    const u16* B0 = Bg + (size_t)srow * ldb + kgp * 8;
    const u16* B1 = Bg + (size_t)(srow + 128) * ldb + kgp * 8;
    u16* Al = lds;
    u16* Bl = lds + 32768;

    // prologue: (0,Ak0)(0,Bk0)(0,Ak1)(0,Bk1)(1,Ak0)(1,Bk0) = 12 loads/thread
    stage_half(A0,      A1,      Al,         tid);
    stage_half(B0,      B1,      Bl,         tid);
    stage_half(A0 + 32, A1 + 32, Al + 8192,  tid);
    stage_half(B0 + 32, B1 + 32, Bl + 8192,  tid);
    stage_half(A0 + 64, A1 + 64, Al + 16384, tid);
    stage_half(B0 + 64, B1 + 64, Bl + 16384, tid);

    short8 bv[4];
#pragma unroll 2
    for (int t = 0; t < NT - 1; ++t) {
        const int p  = (t & 1) * 2;
        const int pn = 2 - p;
        const u16* Ap0 = Al + p * 8192;
        const u16* Ap1 = Al + p * 8192 + 8192;
        const u16* Bp0 = Bl + p * 8192;
        const u16* Bp1 = Bl + p * 8192 + 8192;
        const size_t o1 = (size_t)(t + 1) * 64;
        const size_t o2 = (size_t)(t + 2) * 64;
        VM_WAIT(8); S_BAR();
        stage_half(A0 + o1 + 32, A1 + o1 + 32, Al + (pn + 1) * 8192, tid);
        phase16<0, true >(Ap0, Bp0, arow, brow, ln, quad, bv, acc);
        stage_half(B0 + o1 + 32, B1 + o1 + 32, Bl + (pn + 1) * 8192, tid);
        phase16<4, false>(Ap0, Bp0, arow, brow, ln, quad, bv, acc);
        VM_WAIT(8); S_BAR();
        if (t + 2 < NT) stage_half(A0 + o2, A1 + o2, Al + p * 8192, tid);
        phase16<0, true >(Ap1, Bp1, arow, brow, ln, quad, bv, acc);
        if (t + 2 < NT) stage_half(B0 + o2, B1 + o2, Bl + p * 8192, tid);
        phase16<4, false>(Ap1, Bp1, arow, brow, ln, quad, bv, acc);
    }
    {   // peel t = NT-1: outstanding = {(t,Ak1),(t,Bk1)} = 4 loads
        const int p = ((NT - 1) & 1) * 2;
        const u16* Ap0 = Al + p * 8192;
        const u16* Ap1 = Al + p * 8192 + 8192;
        const u16* Bp0 = Bl + p * 8192;
        const u16* Bp1 = Bl + p * 8192 + 8192;
        VM_WAIT(4); S_BAR();
        phase16<0, true >(Ap0, Bp0, arow, brow, ln, quad, bv, acc);
        phase16<4, false>(Ap0, Bp0, arow, brow, ln, quad, bv, acc);
        VM_WAIT(0); S_BAR();
        phase16<0, true >(Ap1, Bp1, arow, brow, ln, quad, bv, acc);
        phase16<4, false>(Ap1, Bp1, arow, brow, ln, quad, bv, acc);
    }
}

// ===========================================================================
// Epilogue stores for the 256x256 tile (LDS bounce -> contiguous dwordx4).
// ===========================================================================
template <typename F>
__device__ __forceinline__ void store_rm256(u16* smem, u16* gbase, size_t ldc,
                                            int wm, int wn, int ln, int quad,
                                            int tid, F val) {
    for (int half = 0; half < 2; half++) {
        __syncthreads();
        if (wm == half) {
#pragma unroll
            for (int mt = 0; mt < 8; mt++)
#pragma unroll
                for (int nt = 0; nt < 4; nt++)
#pragma unroll
                    for (int r = 0; r < 4; r++)
                        smem[(mt * 16 + quad * 4 + r) * 264 + wn * 64 + nt * 16 + ln] =
                            val(mt, nt, r);
        }
        __syncthreads();
#pragma unroll
        for (int j = 0; j < 8; j++) {
            int flat = j * 512 + tid;
            int row = flat >> 5, c = flat & 31;
            *(uint4*)&gbase[(size_t)(half * 128 + row) * ldc + c * 8] =
                *(const uint4*)&smem[row * 264 + c * 8];
        }
    }
}

template <typename F4>
__device__ __forceinline__ void store_tr256(u16* smem, u16* gbase, size_t ldg,
                                            int wm, int wn, int ln, int quad,
                                            int tid, F4 val4) {
    for (int qr = 0; qr < 4; qr++) {
        __syncthreads();
        if (wn == qr) {
#pragma unroll
            for (int mt = 0; mt < 8; mt++)
#pragma unroll
                for (int nt = 0; nt < 4; nt++) {
                    ushort4 v = val4(mt, nt);
                    *(ushort4*)&smem[(nt * 16 + ln) * 264 + wm * 128 + mt * 16 + quad * 4] = v;
                }
        }
        __syncthreads();
#pragma unroll
        for (int j = 0; j < 4; j++) {
            int flat = j * 512 + tid;
            int c = flat >> 5, r8 = flat & 31;
            *(uint4*)&gbase[(size_t)(qr * 64 + c) * ldg + r8 * 8] =
                *(const uint4*)&smem[c * 264 + r8 * 8];
        }
    }
}

template <typename F>
__device__ __forceinline__ void store_rm256_f32(float* smem, float* gbase, size_t ldc,
                                                int wm, int wn, int ln, int quad,
                                                int tid, F val) {
    for (int c4 = 0; c4 < 4; c4++) {
        __syncthreads();
        if (wm == (c4 >> 1)) {
#pragma unroll
            for (int i = 0; i < 4; i++)
#pragma unroll
                for (int nt = 0; nt < 4; nt++)
#pragma unroll
                    for (int r = 0; r < 4; r++)
                        smem[(i * 16 + quad * 4 + r) * 260 + wn * 64 + nt * 16 + ln] =
                            val((c4 & 1) * 4 + i, nt, r);
        }
        __syncthreads();
#pragma unroll
        for (int j = 0; j < 8; j++) {
            int flat = j * 512 + tid;
            int row = flat >> 6, q = flat & 63;
            *(float4*)&gbase[(size_t)(c4 * 64 + row) * ldc + q * 4] =
                *(const float4*)&smem[row * 260 + q * 4];
        }
    }
}

// ===========================================================================
// Cast f32 -> bf16.
// ===========================================================================
__global__ __launch_bounds__(256) void k_cast_bf16(
    const float* __restrict__ x, u16* __restrict__ o) {
    size_t i = ((size_t)blockIdx.x * 256 + threadIdx.x) * 4;
    float4 v = *(const float4*)&x[i];
    ushort4 p;
    p.x = f2bf(v.x); p.y = f2bf(v.y); p.z = f2bf(v.z); p.w = f2bf(v.w);
    *(ushort4*)&o[i] = p;
}

// ---------------------------------------------------------------------------
// Prep (one launch): z=0 Wq->Wqkt rows 0-255, z=1 Wk->Wqkt rows 256-511,
// z=2 Wv cast -> Wv16, z=3 Wd->Wdt, z=4 bias prep.
// ---------------------------------------------------------------------------
__global__ __launch_bounds__(256) void k_prep(
    const float* __restrict__ Wq, const float* __restrict__ Wk,
    const float* __restrict__ Wv, const float* __restrict__ Wd,
    const float* __restrict__ bv, const float* __restrict__ bd,
    const float* __restrict__ bq, const float* __restrict__ bk,
    u16* __restrict__ Wqkt, u16* __restrict__ Wv16, u16* __restrict__ Wdt,
    float* __restrict__ bc, float* __restrict__ bqk) {
    const int z = blockIdx.z;
    const int t = threadIdx.x;
    if (z == 4) {
        int id = blockIdx.y * 32 + blockIdx.x;
        if (id < 16) {
            __shared__ float red[4][64];
            int n = id * 64 + (t & 63);
            int dc = t >> 6;
            float s = 0.f;
            for (int d = dc * 256; d < dc * 256 + 256; d++)
                s += bv[d] * Wd[(size_t)d * 1024 + n];
            red[dc][t & 63] = s;
            __syncthreads();
            if (dc == 0) bc[n] = bd[n] + red[0][t & 63] + red[1][t & 63] + red[2][t & 63] + red[3][t & 63];
        } else if (id == 16) {
            for (int i = t; i < 512; i += 256) {
                float v = 0.f;
                if (i < KREAL) v = bq[i];
                else if (i >= 256 && i < 256 + KREAL) v = bk[i - 256];
                bqk[i] = v;
            }
        }
        return;
    }
    __shared__ u16 tile[32][33];
    int k0 = blockIdx.x * 32, n0 = blockIdx.y * 32;
    int tx = t & 31, ty = t >> 5;
    if (z == 2) {
        for (int i = ty; i < 32; i += 8) {
            size_t idx = (size_t)(k0 + i) * 1024 + n0 + tx;
            Wv16[idx] = f2bf(Wv[idx]);
        }
        return;
    }
    const float* W; u16* out; int N, Npad, rowoff;
    if (z == 0)      { W = Wq; out = Wqkt; N = KREAL; Npad = 256;  rowoff = 0;   }
    else if (z == 1) { W = Wk; out = Wqkt; N = KREAL; Npad = 256;  rowoff = 256; }
    else             { W = Wd; out = Wdt;  N = 1024;  Npad = 1024; rowoff = 0;   }
    if (n0 >= Npad) return;
    for (int i = ty; i < 32; i += 8) {
        int n = n0 + tx;
        tile[i][tx] = (n < N) ? f2bf(W[(size_t)(k0 + i) * N + n]) : (u16)0;
    }
    __syncthreads();
    for (int i = ty; i < 32; i += 8) {
        int n = n0 + i;
        if (n < Npad) out[(size_t)(rowoff + n) * 1024 + k0 + tx] = tile[tx][i];
    }
}

// ---------------------------------------------------------------------------
// Small GEMM (64x64 tiles): Wvdt[j][i] = sum_k Wv[i][k]*Wd[k][j].
// ---------------------------------------------------------------------------
__global__ __launch_bounds__(256) void k_gemm64(
    const u16* __restrict__ A, const u16* __restrict__ Bt,
    u16* __restrict__ C, int ldc) {
    __shared__ u16 As[64 * 64];
    __shared__ u16 Bs[64 * 64];
    const int tid = threadIdx.x;
    const int m0 = blockIdx.x * 64, n0 = blockIdx.y * 64;
    const int lane = tid & 63, w = tid >> 6;
    const int ln = lane & 15, quad = lane >> 4;

    floatx4 acc[4];
    floatx4 zero = {0.f, 0.f, 0.f, 0.f};
#pragma unroll
    for (int nt = 0; nt < 4; nt++) acc[nt] = zero;

    for (int kt = 0; kt < 16; kt++) {
        __syncthreads();
        stage64(A + (size_t)m0 * 1024 + kt * 64, 1024, As, tid);
        stage64(Bt + (size_t)n0 * 1024 + kt * 64, 1024, Bs, tid);
        __syncthreads();
#pragma unroll
        for (int kk = 0; kk < 2; kk++) {
            short8 av = frag(As, w * 16 + ln, kk * 4 + quad);
#pragma unroll
            for (int nt = 0; nt < 4; nt++) {
                short8 bvf = frag(Bs, nt * 16 + ln, kk * 4 + quad);
                acc[nt] = __builtin_amdgcn_mfma_f32_16x16x32_bf16(av, bvf, acc[nt], 0, 0, 0);
            }
        }
    }
    const int row0 = m0 + w * 16 + quad * 4;
#pragma unroll
    for (int nt = 0; nt < 4; nt++) {
        const int col = n0 + nt * 16 + ln;
        ushort4 pk;
        pk.x = f2bf(acc[nt][0]); pk.y = f2bf(acc[nt][1]);
        pk.z = f2bf(acc[nt][2]); pk.w = f2bf(acc[nt][3]);
        *reinterpret_cast<ushort4*>(&C[(size_t)col * ldc + row0]) = pk;
    }
}

// ---------------------------------------------------------------------------
// Merged projection, 256x256 8-phase core.
// by<2: qk region (B=Wqkt), cols by*256, +bqk -> qkp row-major ld 512.
// by>=2: u region (B=Wvdt), cols (by-2)*256 -> ut[b][d][s] transposed.
// grid (64, 6), 512 threads.
// ---------------------------------------------------------------------------
__global__ __launch_bounds__(512, 2) void k_proj2(
    const u16* __restrict__ A, const u16* __restrict__ Wqkt,
    const u16* __restrict__ Wvdt, const float* __restrict__ bqk,
    u16* __restrict__ qkp, u16* __restrict__ ut) {
    __shared__ __align__(16) u16 lds[65536];
    const int tid = threadIdx.x;
    const int m0 = blockIdx.x * 256;
    const int by = blockIdx.y;
    const int lane = tid & 63, w = tid >> 6;
    const int wm = w >> 2, wn = w & 3;
    const int ln = lane & 15, quad = lane >> 4;

    floatx4 acc[8][4];
    floatx4 zero = {0.f, 0.f, 0.f, 0.f};
#pragma unroll
    for (int mt = 0; mt < 8; mt++)
#pragma unroll
        for (int nt = 0; nt < 4; nt++) acc[mt][nt] = zero;

    const u16* Ag = A + (size_t)m0 * 1024;
    const int n0 = (by < 2) ? by * 256 : (by - 2) * 256;
    const u16* Bg = (by < 2) ? (Wqkt + (size_t)n0 * 1024) : (Wvdt + (size_t)n0 * 1024);
    gemm_core256<16>(Ag, 1024, Bg, 1024, lds, tid, acc);

    if (by < 2) {
        float b4[4];
#pragma unroll
        for (int nt = 0; nt < 4; nt++) b4[nt] = bqk[n0 + wn * 64 + nt * 16 + ln];
        store_rm256(lds, qkp + (size_t)m0 * 512 + n0, 512, wm, wn, ln, quad, tid,
            [&](int mt, int nt, int r) -> u16 {
                return f2bf(acc[mt][nt][r] + b4[nt]);
            });
    } else {
        int b = m0 >> 11, s0loc = m0 & 2047;
        store_tr256(lds, ut + ((size_t)b * DD + n0) * SS + s0loc, SS, wm, wn, ln, quad, tid,
            [&](int mt, int nt) -> ushort4 {
                ushort4 pk;
                pk.x = f2bf(acc[mt][nt][0]); pk.y = f2bf(acc[mt][nt][1]);
                pk.z = f2bf(acc[mt][nt][2]); pk.w = f2bf(acc[mt][nt][3]);
                return pk;
            });
    }
}

// ---------------------------------------------------------------------------
// QK GEMM (all 8 batches): P = bf16(exp(q.k - 30)); row sums via atomics.
// grid (8, 8, 8), 512 threads.
// ---------------------------------------------------------------------------
__global__ __launch_bounds__(512, 2) void k_qk2(
    const u16* __restrict__ qkp, u16* __restrict__ P, float* __restrict__ lg) {
    __shared__ __align__(16) u16 lds[65536];
    const int tid = threadIdx.x;
    const int s0 = blockIdx.x * 256, t0 = blockIdx.y * 256, bb = blockIdx.z;
    const int lane = tid & 63, w = tid >> 6;
    const int wm = w >> 2, wn = w & 3;
    const int ln = lane & 15, quad = lane >> 4;

    floatx4 acc[8][4];
    floatx4 zero = {0.f, 0.f, 0.f, 0.f};
#pragma unroll
    for (int mt = 0; mt < 8; mt++)
#pragma unroll
        for (int nt = 0; nt < 4; nt++) acc[mt][nt] = zero;

    gemm_core256<4>(qkp + ((size_t)bb * SS + s0) * 512, 512,
                    qkp + ((size_t)bb * SS + t0) * 512 + 256, 512, lds, tid, acc);

    // exp in place, then row-sums
#pragma unroll
    for (int mt = 0; mt < 8; mt++)
#pragma unroll
        for (int nt = 0; nt < 4; nt++)
#pragma unroll
            for (int r = 0; r < 4; r++)
                acc[mt][nt][r] = __expf(acc[mt][nt][r] - 30.f);

#pragma unroll
    for (int mt = 0; mt < 8; mt++) {
#pragma unroll
        for (int r = 0; r < 4; r++) {
            float rs = acc[mt][0][r] + acc[mt][1][r] + acc[mt][2][r] + acc[mt][3][r];
            rs += __shfl_xor(rs, 1);
            rs += __shfl_xor(rs, 2);
            rs += __shfl_xor(rs, 4);
            rs += __shfl_xor(rs, 8);
            if (ln == 0)
                atomicAdd(&lg[(size_t)bb * SS + s0 + wm * 128 + mt * 16 + quad * 4 + r], rs);
        }
    }

    store_rm256(lds, P + (size_t)bb * SS * SS + (size_t)s0 * SS + t0, SS,
                wm, wn, ln, quad, tid,
        [&](int mt, int nt, int r) -> u16 { return f2bf(acc[mt][nt][r]); });
}

// ---------------------------------------------------------------------------
// Final GEMM (all 8 batches, one launch): out = (P.ut)/l + bc + x  (f32,
// written straight into d_out; LayerNorm runs in-place afterwards).
// grid (8, 4, 8), 512 threads.
// ---------------------------------------------------------------------------
__global__ __launch_bounds__(512, 2) void k_h2(
    const u16* __restrict__ P, const u16* __restrict__ ut,
    const float* __restrict__ lg, const float* __restrict__ bc,
    const float* __restrict__ xres, float* __restrict__ out) {
    __shared__ __align__(16) u16 lds[65536];
    const int tid = threadIdx.x;
    const int s0 = blockIdx.x * 256, d0 = blockIdx.y * 256, bb = blockIdx.z;
    const int lane = tid & 63, w = tid >> 6;
    const int wm = w >> 2, wn = w & 3;
    const int ln = lane & 15, quad = lane >> 4;

    floatx4 acc[8][4];
    floatx4 zero = {0.f, 0.f, 0.f, 0.f};
#pragma unroll
    for (int mt = 0; mt < 8; mt++)
#pragma unroll
        for (int nt = 0; nt < 4; nt++) acc[mt][nt] = zero;

    gemm_core256<32>(P + ((size_t)bb * SS + s0) * SS, SS,
                     ut + ((size_t)bb * DD + d0) * SS, SS, lds, tid, acc);

    float b4[4];
#pragma unroll
    for (int nt = 0; nt < 4; nt++) b4[nt] = bc[d0 + wn * 64 + nt * 16 + ln];
    float inv[8][4];
#pragma unroll
    for (int mt = 0; mt < 8; mt++)
#pragma unroll
        for (int r = 0; r < 4; r++)
            inv[mt][r] = 1.f / lg[(size_t)bb * SS + s0 + wm * 128 + mt * 16 + quad * 4 + r];

    store_rm256_f32((float*)lds, out + ((size_t)bb * SS + s0) * DD + d0, DD,
                    wm, wn, ln, quad, tid,
        [&](int mt, int nt, int r) -> float {
            size_t grow = (size_t)bb * SS + s0 + wm * 128 + mt * 16 + quad * 4 + r;
            int col = d0 + wn * 64 + nt * 16 + ln;
            return acc[mt][nt][r] * inv[mt][r] + b4[nt] + xres[grow * DD + col];
        });
}

// ---------------------------------------------------------------------------
// LayerNorm over last dim (1024), f32 IN-PLACE on d_out. Each block owns 4
// rows exclusively -> no cross-block hazard.
// ---------------------------------------------------------------------------
__global__ __launch_bounds__(256) void k_ln_f32(
    float* __restrict__ io, const float* __restrict__ gamma,
    const float* __restrict__ beta) {
    const int tid = threadIdx.x;
    const int lane = tid & 63, w = tid >> 6;
    const size_t row = (size_t)blockIdx.x * 4 + w;
    float* rp = io + row * DD;

    float v[16];
#pragma unroll
    for (int j = 0; j < 4; j++) {
        float4 t = *(const float4*)&rp[j * 256 + lane * 4];
        v[j * 4 + 0] = t.x; v[j * 4 + 1] = t.y; v[j * 4 + 2] = t.z; v[j * 4 + 3] = t.w;
    }
    float s = 0.f, sq = 0.f;
#pragma unroll
    for (int i = 0; i < 16; i++) { s += v[i]; sq += v[i] * v[i]; }
#pragma unroll
    for (int msk = 1; msk < 64; msk <<= 1) {
        s  += __shfl_xor(s,  msk, 64);
        sq += __shfl_xor(sq, msk, 64);
    }
    float mean = s * (1.f / 1024.f);
    float var  = sq * (1.f / 1024.f) - mean * mean;
    float rstd = rsqrtf(fmaxf(var, 0.f) + 1e-12f);
#pragma unroll
    for (int j = 0; j < 4; j++) {
        float4 g  = *(const float4*)&gamma[j * 256 + lane * 4];
        float4 bt = *(const float4*)&beta [j * 256 + lane * 4];
        float4 o;
        o.x = g.x * (v[j * 4 + 0] - mean) * rstd + bt.x;
        o.y = g.y * (v[j * 4 + 1] - mean) * rstd + bt.y;
        o.z = g.z * (v[j * 4 + 2] - mean) * rstd + bt.z;
        o.w = g.w * (v[j * 4 + 3] - mean) * rstd + bt.w;
        *(float4*)&rp[j * 256 + lane * 4] = o;
    }
}

// ---------------------------------------------------------------------------
extern "C" void kernel_launch(void* const* d_in, const int* in_sizes, int n_in,
                              void* d_out, int out_size, void* d_ws, size_t ws_size,
                              hipStream_t stream) {
    const float* x     = (const float*)d_in[0];
    const float* Wq    = (const float*)d_in[2];
    const float* bq    = (const float*)d_in[3];
    const float* Wk    = (const float*)d_in[4];
    const float* bk    = (const float*)d_in[5];
    const float* Wv    = (const float*)d_in[6];
    const float* bv    = (const float*)d_in[7];
    const float* Wd    = (const float*)d_in[8];
    const float* bd    = (const float*)d_in[9];
    const float* gamma = (const float*)d_in[10];
    const float* beta  = (const float*)d_in[11];
    float* out = (float*)d_out;

    // Workspace (~112.1 MB used, 122.7 proven usable):
    //   [0, 16.78M)        qkp  [16384][512] bf16
    //   [16.78M, 50.33M)   ut   [8][1024][2048] bf16
    //   [50.33M, 117.44M)  P    [8][2048][2048] bf16
    //       aliases (dead before qk writes P):
    //         x16  @ 50.33M (33.55M), Wv16 @ 83.89M, Wvdt @ 85.98M,
    //         Wdt @ 88.08M, Wqkt @ 90.18M
    //   [117.44M, ..)      lg (64K), bc (4K), bqk (2K)
    // y buffer eliminated: k_h2 writes f32 directly to d_out, LN in-place.
    char* ws = (char*)d_ws;
    u16*   qkp  = (u16*)(ws + 0);
    u16*   ut   = (u16*)(ws + 16777216);
    u16*   P    = (u16*)(ws + 50331648);
    u16*   x16  = (u16*)(ws + 50331648);
    u16*   Wv16 = (u16*)(ws + 83886080);
    u16*   Wvdt = (u16*)(ws + 85983232);
    u16*   Wdt  = (u16*)(ws + 88080384);
    u16*   Wqkt = (u16*)(ws + 90177536);
    float* lg   = (float*)(ws + 117440512);
    float* bc   = (float*)(ws + 117506048);
    float* bqk  = (float*)(ws + 117510144);

    k_cast_bf16<<<dim3(16384), dim3(256), 0, stream>>>(x, x16);
    k_prep<<<dim3(32, 32, 5), dim3(256), 0, stream>>>(Wq, Wk, Wv, Wd, bv, bd, bq, bk,
                                                      Wqkt, Wv16, Wdt, bc, bqk);
    k_gemm64<<<dim3(16, 16), dim3(256), 0, stream>>>(Wv16, Wdt, Wvdt, 1024);

    k_proj2<<<dim3(64, 6), dim3(512), 0, stream>>>(x16, Wqkt, Wvdt, bqk, qkp, ut);

    hipMemsetAsync(lg, 0, (size_t)BB * SS * sizeof(float), stream);

    k_qk2<<<dim3(8, 8, 8), dim3(512), 0, stream>>>(qkp, P, lg);
    k_h2 <<<dim3(8, 4, 8), dim3(512), 0, stream>>>(P, ut, lg, bc, x, out);

    k_ln_f32<<<dim3(4096), dim3(256), 0, stream>>>(out, gamma, beta);
}